// Round 2
// baseline (965.944 us; speedup 1.0000x reference)
//
#include <hip/hip_runtime.h>
#include <math.h>

// VectorQuantizer: 131072 rows of D=64, argmin over K=1024 codes,
// gather codebook + histogram -> perplexity.
// Layout: inputs NCHW [32,64,64,64]; flat row = n*4096 + h*64 + w,
// channel c at offset (n<<18) + (c<<12) + hw.

#define NROWS (32 * 64 * 64)   // 131072
#define KCODES 1024
#define DIM 64
#define ROWS_PER_BLOCK 128     // 2 threads per row (2-way K-split)
#define KCHUNK 512

// ---- kernel 1: codebook squared norms (match ref: sum(c*c) per code) ----
__global__ __launch_bounds__(256) void vq_cc_kernel(const float* __restrict__ cb,
                                                    float* __restrict__ cc) {
    int k = blockIdx.x * 256 + threadIdx.x;
    if (k < KCODES) {
        const float* c = cb + k * DIM;
        float a0 = 0.f, a1 = 0.f, a2 = 0.f, a3 = 0.f;
        #pragma unroll
        for (int i = 0; i < DIM; i += 4) {
            a0 = fmaf(c[i + 0], c[i + 0], a0);
            a1 = fmaf(c[i + 1], c[i + 1], a1);
            a2 = fmaf(c[i + 2], c[i + 2], a2);
            a3 = fmaf(c[i + 3], c[i + 3], a3);
        }
        cc[k] = (a0 + a1) + (a2 + a3);
    }
}

// ---- kernel 2: main quantization ----
// 2 threads per row: chunk 0 scans k in [0,512), chunk 1 scans [512,1024).
// Waves 0,1 = chunk 0 (rows 0..127 of block); waves 2,3 = chunk 1.
// launch_bounds(256,4): 128-VGPR budget so xv[64] is register-resident;
// 1024 blocks * 4 waves = 16 waves/CU = 4 waves/SIMD (the VGPR-cap max).
__global__ __launch_bounds__(256, 4) void vq_main_kernel(const float* __restrict__ x,
                                                         const float* __restrict__ cb,
                                                         const float* __restrict__ cc,
                                                         float* __restrict__ out,
                                                         unsigned int* __restrict__ counts) {
    __shared__ float s_d[ROWS_PER_BLOCK];
    __shared__ int   s_k[ROWS_PER_BLOCK];

    int t = threadIdx.x;
    int row_local = t & (ROWS_PER_BLOCK - 1);
    int chunk = t >> 7;
    int row = blockIdx.x * ROWS_PER_BLOCK + row_local;
    int n  = row >> 12;
    int hw = row & 4095;
    const float* xp = x + ((size_t)n << 18) + hw;

    float xv[DIM];
    #pragma unroll
    for (int c = 0; c < DIM; c++) xv[c] = xp[(size_t)c << 12];

    // ||x||^2 in fp32 (8-accumulator + pairwise combine; sub-ulp diffs are
    // absorbed by the +s quantization at magnitude ~64)
    float r[8];
    #pragma unroll
    for (int j = 0; j < 8; j++) r[j] = 0.f;
    #pragma unroll
    for (int i = 0; i < DIM; i += 8) {
        #pragma unroll
        for (int j = 0; j < 8; j++) r[j] = fmaf(xv[i + j], xv[i + j], r[j]);
    }
    float s = ((r[0] + r[1]) + (r[2] + r[3])) + ((r[4] + r[5]) + (r[6] + r[7]));

    int k0 = chunk * KCHUNK;
    float dmin = 3.402823466e+38f;
    int   kmin = k0;
    for (int k = k0; k < k0 + KCHUNK; k++) {
        const float* cbk = cb + k * DIM;   // wave-uniform -> s_load stream
        float a0 = 0.f, a1 = 0.f, a2 = 0.f, a3 = 0.f;
        #pragma unroll
        for (int c = 0; c < DIM; c += 4) {
            a0 = fmaf(xv[c + 0], cbk[c + 0], a0);
            a1 = fmaf(xv[c + 1], cbk[c + 1], a1);
            a2 = fmaf(xv[c + 2], cbk[c + 2], a2);
            a3 = fmaf(xv[c + 3], cbk[c + 3], a3);
        }
        float dot = (a0 + a1) + (a2 + a3);
        // match ref association: (s + cc[k]) - 2*dot, fp32 each step
        float d = (s + cc[k]) - 2.0f * dot;
        if (d < dmin) { dmin = d; kmin = k; }   // strict < keeps first index
    }

    // cross-chunk argmin combine; ties -> chunk 0 (lower k), matching
    // global first-index semantics since chunk0 covers lower k.
    if (chunk == 1) { s_d[row_local] = dmin; s_k[row_local] = kmin; }
    __syncthreads();
    if (chunk == 0) {
        float d1 = s_d[row_local];
        if (d1 < dmin) { dmin = d1; kmin = s_k[row_local]; }

        // straight-through value: x + (q - x), fp32 op order mimics reference
        const float* q = cb + kmin * DIM;
        float* op = out + ((size_t)n << 18) + hw;
        #pragma unroll
        for (int c = 0; c < DIM; c++) {
            float xc = xv[c];
            op[(size_t)c << 12] = xc + (q[c] - xc);
        }
        atomicAdd(&counts[kmin], 1u);
    }
}

// ---- kernel 3: perplexity from histogram ----
__global__ __launch_bounds__(1024) void vq_ppl_kernel(const unsigned int* __restrict__ counts,
                                                      float* __restrict__ out) {
    __shared__ float red[16];
    int k = threadIdx.x;
    float p = (float)counts[k] / (float)NROWS;
    float v = p * logf(p + 1e-10f);
    #pragma unroll
    for (int off = 32; off > 0; off >>= 1) v += __shfl_down(v, off, 64);
    int wave = k >> 6;
    int lane = k & 63;
    if (lane == 0) red[wave] = v;
    __syncthreads();
    if (k == 0) {
        float sum = 0.f;
        #pragma unroll
        for (int w = 0; w < 16; w++) sum += red[w];
        float ppl = expf(-sum);
        out[8388608] = 0.0f;   // loss (eval branch)
        out[8388609] = ppl;    // perplexity
    }
}

extern "C" void kernel_launch(void* const* d_in, const int* in_sizes, int n_in,
                              void* d_out, int out_size, void* d_ws, size_t ws_size,
                              hipStream_t stream) {
    const float* x  = (const float*)d_in[0];
    const float* cb = (const float*)d_in[1];
    float* out = (float*)d_out;

    unsigned int* counts = (unsigned int*)d_ws;                 // 1024 u32
    float*        cc     = (float*)((char*)d_ws + 4096);        // 1024 f32

    hipMemsetAsync(d_ws, 0, 4096, stream);                      // zero histogram
    vq_cc_kernel<<<(KCODES + 255) / 256, 256, 0, stream>>>(cb, cc);
    vq_main_kernel<<<NROWS / ROWS_PER_BLOCK, 256, 0, stream>>>(x, cb, cc, out, counts);
    vq_ppl_kernel<<<1, 1024, 0, stream>>>(counts, out);
}

// Round 3
// 333.337 us; speedup vs baseline: 2.8978x; 2.8978x over previous
//
#include <hip/hip_runtime.h>
#include <math.h>

// VectorQuantizer: 131072 rows of D=64, argmin over K=1024 codes,
// gather codebook + histogram -> perplexity.
// Layout: inputs NCHW [32,64,64,64]; flat row = n*4096 + h*64 + w,
// channel c at offset (n<<18) + (c<<12) + hw.
//
// v3: x pinned in VGPRs (asm liveness trick), codebook staged in LDS in
// 32KB tiles (double-buffered, reg-prefetch issued before compute),
// wave-uniform broadcast ds_read_b128 for codebook. Dot arithmetic is
// bit-identical to the absmax==0.0 round-1 kernel.

#define NROWS (32 * 64 * 64)   // 131072
#define KCODES 1024
#define DIM 64
#define TK 128                 // codes per LDS tile (32 KB)
#define NTILES (KCODES / TK)   // 8

// ---- kernel 1: codebook squared norms (bit-identical to round 1) ----
__global__ __launch_bounds__(256) void vq_cc_kernel(const float* __restrict__ cb,
                                                    float* __restrict__ cc) {
    int k = blockIdx.x * 256 + threadIdx.x;
    if (k < KCODES) {
        const float* c = cb + k * DIM;
        float a0 = 0.f, a1 = 0.f, a2 = 0.f, a3 = 0.f;
        #pragma unroll
        for (int i = 0; i < DIM; i += 4) {
            a0 = fmaf(c[i + 0], c[i + 0], a0);
            a1 = fmaf(c[i + 1], c[i + 1], a1);
            a2 = fmaf(c[i + 2], c[i + 2], a2);
            a3 = fmaf(c[i + 3], c[i + 3], a3);
        }
        cc[k] = (a0 + a1) + (a2 + a3);
    }
}

// ---- kernel 2: main quantization ----
// 1 thread per row; row lives in 16 float4 VGPRs (pinned). Codebook tile
// (128 codes, 32 KB) in LDS, read broadcast (wave-uniform address).
// Double-buffered: next tile global-loaded into regs BEFORE compute of
// the current tile, written to the other LDS buffer after the barrier.
__global__ __launch_bounds__(256, 2) void vq_main_kernel(const float* __restrict__ x,
                                                         const float* __restrict__ cb,
                                                         const float* __restrict__ cc,
                                                         float* __restrict__ out,
                                                         unsigned int* __restrict__ counts) {
    __shared__ float sb[2][TK * DIM];   // 2 x 32 KB
    __shared__ float scc[2][TK];        // 2 x 512 B

    int t = threadIdx.x;
    int row = blockIdx.x * 256 + t;
    int n  = row >> 12;
    int hw = row & 4095;
    const float* xp = x + ((size_t)n << 18) + hw;

    // load row (coalesced across lanes per channel)
    float4 xv[16];
    #pragma unroll
    for (int j = 0; j < 16; ++j) {
        xv[j].x = xp[(size_t)(4 * j + 0) << 12];
        xv[j].y = xp[(size_t)(4 * j + 1) << 12];
        xv[j].z = xp[(size_t)(4 * j + 2) << 12];
        xv[j].w = xp[(size_t)(4 * j + 3) << 12];
    }
    // pin the row in VGPRs: asm outputs can't be rematerialized from memory,
    // so the compiler must keep these 64 values register-resident.
    #pragma unroll
    for (int j = 0; j < 16; ++j)
        asm volatile("" : "+v"(xv[j].x), "+v"(xv[j].y), "+v"(xv[j].z), "+v"(xv[j].w));

    // ||x||^2 — identical association to round 1 (8 accumulators, pairwise)
    float r0 = 0.f, r1 = 0.f, r2 = 0.f, r3 = 0.f, r4 = 0.f, r5 = 0.f, r6 = 0.f, r7 = 0.f;
    #pragma unroll
    for (int i = 0; i < 16; i += 2) {
        r0 = fmaf(xv[i].x, xv[i].x, r0);
        r1 = fmaf(xv[i].y, xv[i].y, r1);
        r2 = fmaf(xv[i].z, xv[i].z, r2);
        r3 = fmaf(xv[i].w, xv[i].w, r3);
        r4 = fmaf(xv[i + 1].x, xv[i + 1].x, r4);
        r5 = fmaf(xv[i + 1].y, xv[i + 1].y, r5);
        r6 = fmaf(xv[i + 1].z, xv[i + 1].z, r6);
        r7 = fmaf(xv[i + 1].w, xv[i + 1].w, r7);
    }
    float s = ((r0 + r1) + (r2 + r3)) + ((r4 + r5) + (r6 + r7));

    const float4* cb4 = (const float4*)cb;   // codebook as float4[KCODES*16]

    // ---- stage tile 0 ----
    float4 pre[8];
    float  ccv;
    #pragma unroll
    for (int i = 0; i < 8; ++i) pre[i] = cb4[i * 256 + t];
    ccv = (t < TK) ? cc[t] : 0.f;
    {
        float4* sb0 = (float4*)sb[0];
        #pragma unroll
        for (int i = 0; i < 8; ++i) sb0[i * 256 + t] = pre[i];
        if (t < TK) scc[0][t] = ccv;
    }
    __syncthreads();

    float dmin = 3.402823466e+38f;
    int   kmin = 0;

    for (int tile = 0; tile < NTILES; ++tile) {
        int cur = tile & 1;
        // prefetch next tile into regs — issued before compute so HBM/L2
        // latency hides under the FMA stream (T14 issue-early)
        if (tile + 1 < NTILES) {
            #pragma unroll
            for (int i = 0; i < 8; ++i)
                pre[i] = cb4[(size_t)(tile + 1) * (TK * DIM / 4) + i * 256 + t];
            ccv = (t < TK) ? cc[(tile + 1) * TK + t] : 0.f;
        }

        const float4* cbase = (const float4*)sb[cur];
        const float*  ccb   = scc[cur];
        int k0 = tile * TK;

        for (int kk = 0; kk < TK; kk += 2) {
            const float4* c0 = cbase + kk * 16;        // wave-uniform -> broadcast
            const float4* c1 = cbase + kk * 16 + 16;
            float a0 = 0.f, a1 = 0.f, a2 = 0.f, a3 = 0.f;
            float b0 = 0.f, b1 = 0.f, b2 = 0.f, b3 = 0.f;
            #pragma unroll
            for (int j = 0; j < 16; ++j) {
                float4 xj = xv[j];
                float4 ca = c0[j];
                float4 cbv = c1[j];
                a0 = fmaf(xj.x, ca.x, a0);
                a1 = fmaf(xj.y, ca.y, a1);
                a2 = fmaf(xj.z, ca.z, a2);
                a3 = fmaf(xj.w, ca.w, a3);
                b0 = fmaf(xj.x, cbv.x, b0);
                b1 = fmaf(xj.y, cbv.y, b1);
                b2 = fmaf(xj.z, cbv.z, b2);
                b3 = fmaf(xj.w, cbv.w, b3);
            }
            float dot0 = (a0 + a1) + (a2 + a3);
            float dot1 = (b0 + b1) + (b2 + b3);
            // match ref association: (s + cc[k]) - 2*dot, fp32 each step
            float d0 = (s + ccb[kk])     - 2.0f * dot0;
            float d1 = (s + ccb[kk + 1]) - 2.0f * dot1;
            if (d0 < dmin) { dmin = d0; kmin = k0 + kk; }       // strict <
            if (d1 < dmin) { dmin = d1; kmin = k0 + kk + 1; }   // keeps first index
        }
        __syncthreads();   // all waves done reading sb[cur]
        if (tile + 1 < NTILES) {
            int nxt = cur ^ 1;
            float4* sbn = (float4*)sb[nxt];
            #pragma unroll
            for (int i = 0; i < 8; ++i) sbn[i * 256 + t] = pre[i];
            if (t < TK) scc[nxt][t] = ccv;
            __syncthreads();   // sb[nxt] ready for next tile
        }
    }

    // epilogue: straight-through value x + (q - x), bit-identical to round 1
    const float4* q4 = cb4 + (size_t)kmin * 16;
    float* op = out + ((size_t)n << 18) + hw;
    #pragma unroll
    for (int j = 0; j < 16; ++j) {
        float4 q = q4[j];
        op[(size_t)(4 * j + 0) << 12] = xv[j].x + (q.x - xv[j].x);
        op[(size_t)(4 * j + 1) << 12] = xv[j].y + (q.y - xv[j].y);
        op[(size_t)(4 * j + 2) << 12] = xv[j].z + (q.z - xv[j].z);
        op[(size_t)(4 * j + 3) << 12] = xv[j].w + (q.w - xv[j].w);
    }
    atomicAdd(&counts[kmin], 1u);
}

// ---- kernel 3: perplexity from histogram ----
__global__ __launch_bounds__(1024) void vq_ppl_kernel(const unsigned int* __restrict__ counts,
                                                      float* __restrict__ out) {
    __shared__ float red[16];
    int k = threadIdx.x;
    float p = (float)counts[k] / (float)NROWS;
    float v = p * logf(p + 1e-10f);
    #pragma unroll
    for (int off = 32; off > 0; off >>= 1) v += __shfl_down(v, off, 64);
    int wave = k >> 6;
    int lane = k & 63;
    if (lane == 0) red[wave] = v;
    __syncthreads();
    if (k == 0) {
        float sum = 0.f;
        #pragma unroll
        for (int w = 0; w < 16; w++) sum += red[w];
        float ppl = expf(-sum);
        out[8388608] = 0.0f;   // loss (eval branch)
        out[8388609] = ppl;    // perplexity
    }
}

extern "C" void kernel_launch(void* const* d_in, const int* in_sizes, int n_in,
                              void* d_out, int out_size, void* d_ws, size_t ws_size,
                              hipStream_t stream) {
    const float* x  = (const float*)d_in[0];
    const float* cb = (const float*)d_in[1];
    float* out = (float*)d_out;

    unsigned int* counts = (unsigned int*)d_ws;                 // 1024 u32
    float*        cc     = (float*)((char*)d_ws + 4096);        // 1024 f32

    hipMemsetAsync(d_ws, 0, 4096, stream);                      // zero histogram
    vq_cc_kernel<<<(KCODES + 255) / 256, 256, 0, stream>>>(cb, cc);
    vq_main_kernel<<<NROWS / 256, 256, 0, stream>>>(x, cb, cc, out, counts);
    vq_ppl_kernel<<<1, 1024, 0, stream>>>(counts, out);
}

// Round 4
// 279.707 us; speedup vs baseline: 3.4534x; 1.1917x over previous
//
#include <hip/hip_runtime.h>
#include <math.h>

// VectorQuantizer: 131072 rows of D=64, argmin over K=1024 codes,
// gather codebook + histogram -> perplexity.
// Layout: inputs NCHW [32,64,64,64]; flat row = n*4096 + h*64 + w,
// channel c at offset (n<<18) + (c<<12) + hw.
//
// v4: 2 rows per thread (each LDS broadcast read feeds 8 FMAs instead of 4)
// + 2-way K-split so the CU still holds 8 waves. Codebook tiles (64 codes
// per chunk = 32 KB total) double-buffered in LDS, prefetch issued before
// compute (T14). Dot arithmetic bit-identical to the absmax==0.0 kernels.

#define NROWS (32 * 64 * 64)   // 131072
#define KCODES 1024
#define DIM 64
#define TCODES 64              // codes per chunk per tile
#define NTILES 8               // 512 codes per chunk / 64

// ---- kernel 1: codebook squared norms (bit-identical to round 1) ----
__global__ __launch_bounds__(256) void vq_cc_kernel(const float* __restrict__ cb,
                                                    float* __restrict__ cc) {
    int k = blockIdx.x * 256 + threadIdx.x;
    if (k < KCODES) {
        const float* c = cb + k * DIM;
        float a0 = 0.f, a1 = 0.f, a2 = 0.f, a3 = 0.f;
        #pragma unroll
        for (int i = 0; i < DIM; i += 4) {
            a0 = fmaf(c[i + 0], c[i + 0], a0);
            a1 = fmaf(c[i + 1], c[i + 1], a1);
            a2 = fmaf(c[i + 2], c[i + 2], a2);
            a3 = fmaf(c[i + 3], c[i + 3], a3);
        }
        cc[k] = (a0 + a1) + (a2 + a3);
    }
}

// ---- kernel 2: main quantization ----
// Block = 256 threads. chunk = t>>7 (wave-uniform): chunk 0 scans codes
// [0,512), chunk 1 scans [512,1024). Thread owns rows base+rl and
// base+rl+128 (both coalesced across lanes). Tile = 64 codes per chunk
// (2 chunks interleaved in one 32 KB LDS buffer), double-buffered.
__global__ __launch_bounds__(256, 2) void vq_main_kernel(const float* __restrict__ x,
                                                         const float* __restrict__ cb,
                                                         const float* __restrict__ cc,
                                                         float* __restrict__ out,
                                                         unsigned int* __restrict__ counts) {
    __shared__ float4 sb[2][128 * 16];   // 2 x 32 KB: 128 codes x 16 float4
    __shared__ float  s_d[256];
    __shared__ int    s_k[256];

    int t = threadIdx.x;
    int chunk = t >> 7;            // wave-uniform
    int rl = t & 127;
    int ra = blockIdx.x * 256 + rl;
    int rb = ra + 128;
    const float* xa = x + ((size_t)(ra >> 12) << 18) + (ra & 4095);
    const float* xb = x + ((size_t)(rb >> 12) << 18) + (rb & 4095);

    // load both rows (coalesced across lanes per channel)
    float4 xva[16], xvb[16];
    #pragma unroll
    for (int j = 0; j < 16; ++j) {
        xva[j].x = xa[(size_t)(4 * j + 0) << 12];
        xva[j].y = xa[(size_t)(4 * j + 1) << 12];
        xva[j].z = xa[(size_t)(4 * j + 2) << 12];
        xva[j].w = xa[(size_t)(4 * j + 3) << 12];
        xvb[j].x = xb[(size_t)(4 * j + 0) << 12];
        xvb[j].y = xb[(size_t)(4 * j + 1) << 12];
        xvb[j].z = xb[(size_t)(4 * j + 2) << 12];
        xvb[j].w = xb[(size_t)(4 * j + 3) << 12];
    }
    #pragma unroll
    for (int j = 0; j < 16; ++j) {
        asm volatile("" : "+v"(xva[j].x), "+v"(xva[j].y), "+v"(xva[j].z), "+v"(xva[j].w));
        asm volatile("" : "+v"(xvb[j].x), "+v"(xvb[j].y), "+v"(xvb[j].z), "+v"(xvb[j].w));
    }

    // ||x||^2 per row — identical association to rounds 1-3
    float sa, sB;
    {
        float r0 = 0.f, r1 = 0.f, r2 = 0.f, r3 = 0.f, r4 = 0.f, r5 = 0.f, r6 = 0.f, r7 = 0.f;
        #pragma unroll
        for (int i = 0; i < 16; i += 2) {
            r0 = fmaf(xva[i].x, xva[i].x, r0);
            r1 = fmaf(xva[i].y, xva[i].y, r1);
            r2 = fmaf(xva[i].z, xva[i].z, r2);
            r3 = fmaf(xva[i].w, xva[i].w, r3);
            r4 = fmaf(xva[i + 1].x, xva[i + 1].x, r4);
            r5 = fmaf(xva[i + 1].y, xva[i + 1].y, r5);
            r6 = fmaf(xva[i + 1].z, xva[i + 1].z, r6);
            r7 = fmaf(xva[i + 1].w, xva[i + 1].w, r7);
        }
        sa = ((r0 + r1) + (r2 + r3)) + ((r4 + r5) + (r6 + r7));
    }
    {
        float r0 = 0.f, r1 = 0.f, r2 = 0.f, r3 = 0.f, r4 = 0.f, r5 = 0.f, r6 = 0.f, r7 = 0.f;
        #pragma unroll
        for (int i = 0; i < 16; i += 2) {
            r0 = fmaf(xvb[i].x, xvb[i].x, r0);
            r1 = fmaf(xvb[i].y, xvb[i].y, r1);
            r2 = fmaf(xvb[i].z, xvb[i].z, r2);
            r3 = fmaf(xvb[i].w, xvb[i].w, r3);
            r4 = fmaf(xvb[i + 1].x, xvb[i + 1].x, r4);
            r5 = fmaf(xvb[i + 1].y, xvb[i + 1].y, r5);
            r6 = fmaf(xvb[i + 1].z, xvb[i + 1].z, r6);
            r7 = fmaf(xvb[i + 1].w, xvb[i + 1].w, r7);
        }
        sB = ((r0 + r1) + (r2 + r3)) + ((r4 + r5) + (r6 + r7));
    }

    const float4* cb4 = (const float4*)cb;

    // tile staging: slot s = i*256+t -> local code s>>4 (0-63 chunk0,
    // 64-127 chunk1), float4 j = s&15. Coalesced per i.
    float4 pre[8];
    #pragma unroll
    for (int i = 0; i < 8; ++i) {
        int s = i * 256 + t;
        int code = s >> 4, j = s & 15;
        int g = (code < TCODES) ? code : (512 - TCODES + code);   // tile 0
        pre[i] = cb4[g * 16 + j];
    }
    {
        float4* dst = &sb[0][0];
        #pragma unroll
        for (int i = 0; i < 8; ++i) dst[i * 256 + t] = pre[i];
    }
    __syncthreads();

    float dmina = 3.402823466e+38f, dminb = 3.402823466e+38f;
    int   kmina = chunk * 512, kminb = chunk * 512;

    for (int tile = 0; tile < NTILES; ++tile) {
        int cur = tile & 1;
        if (tile + 1 < NTILES) {      // prefetch next tile (issue-early)
            #pragma unroll
            for (int i = 0; i < 8; ++i) {
                int s = i * 256 + t;
                int code = s >> 4, j = s & 15;
                int g = (code < TCODES) ? ((tile + 1) * TCODES + code)
                                        : (512 + (tile + 1) * TCODES + (code - TCODES));
                pre[i] = cb4[g * 16 + j];
            }
        }

        const float4* cl = &sb[cur][(chunk * TCODES) * 16];   // wave-uniform base
        int kg0 = chunk * 512 + tile * TCODES;

        for (int kk = 0; kk < TCODES; ++kk) {
            const float4* c0 = cl + kk * 16;   // uniform -> broadcast ds_read_b128
            float a0 = 0.f, a1 = 0.f, a2 = 0.f, a3 = 0.f;
            float b0 = 0.f, b1 = 0.f, b2 = 0.f, b3 = 0.f;
            #pragma unroll
            for (int j = 0; j < 16; ++j) {
                float4 cj = c0[j];
                a0 = fmaf(xva[j].x, cj.x, a0);
                a1 = fmaf(xva[j].y, cj.y, a1);
                a2 = fmaf(xva[j].z, cj.z, a2);
                a3 = fmaf(xva[j].w, cj.w, a3);
                b0 = fmaf(xvb[j].x, cj.x, b0);
                b1 = fmaf(xvb[j].y, cj.y, b1);
                b2 = fmaf(xvb[j].z, cj.z, b2);
                b3 = fmaf(xvb[j].w, cj.w, b3);
            }
            float dota = (a0 + a1) + (a2 + a3);
            float dotb = (b0 + b1) + (b2 + b3);
            float ccv = cc[kg0 + kk];          // uniform scalar, K$-resident
            float da = (sa + ccv) - 2.0f * dota;
            float db = (sB + ccv) - 2.0f * dotb;
            if (da < dmina) { dmina = da; kmina = kg0 + kk; }   // strict <
            if (db < dminb) { dminb = db; kminb = kg0 + kk; }   // keeps first index
        }
        __syncthreads();
        if (tile + 1 < NTILES) {
            float4* dst = &sb[cur ^ 1][0];
            #pragma unroll
            for (int i = 0; i < 8; ++i) dst[i * 256 + t] = pre[i];
            __syncthreads();
        }
    }

    // cross-chunk argmin combine; ties -> chunk 0 (lower k) = first index.
    if (chunk == 1) {
        s_d[rl] = dmina;       s_k[rl] = kmina;
        s_d[rl + 128] = dminb; s_k[rl + 128] = kminb;
    }
    __syncthreads();
    if (chunk == 0) {
        float d1 = s_d[rl];
        if (d1 < dmina) { dmina = d1; kmina = s_k[rl]; }
        float d2 = s_d[rl + 128];
        if (d2 < dminb) { dminb = d2; kminb = s_k[rl + 128]; }

        // epilogue: straight-through x + (q - x), bit-identical op order
        const float4* qa = cb4 + (size_t)kmina * 16;
        const float4* qb = cb4 + (size_t)kminb * 16;
        float* oa = out + ((size_t)(ra >> 12) << 18) + (ra & 4095);
        float* ob = out + ((size_t)(rb >> 12) << 18) + (rb & 4095);
        #pragma unroll
        for (int j = 0; j < 16; ++j) {
            float4 q = qa[j];
            oa[(size_t)(4 * j + 0) << 12] = xva[j].x + (q.x - xva[j].x);
            oa[(size_t)(4 * j + 1) << 12] = xva[j].y + (q.y - xva[j].y);
            oa[(size_t)(4 * j + 2) << 12] = xva[j].z + (q.z - xva[j].z);
            oa[(size_t)(4 * j + 3) << 12] = xva[j].w + (q.w - xva[j].w);
        }
        #pragma unroll
        for (int j = 0; j < 16; ++j) {
            float4 q = qb[j];
            ob[(size_t)(4 * j + 0) << 12] = xvb[j].x + (q.x - xvb[j].x);
            ob[(size_t)(4 * j + 1) << 12] = xvb[j].y + (q.y - xvb[j].y);
            ob[(size_t)(4 * j + 2) << 12] = xvb[j].z + (q.z - xvb[j].z);
            ob[(size_t)(4 * j + 3) << 12] = xvb[j].w + (q.w - xvb[j].w);
        }
        atomicAdd(&counts[kmina], 1u);
        atomicAdd(&counts[kminb], 1u);
    }
}

// ---- kernel 3: perplexity from histogram ----
__global__ __launch_bounds__(1024) void vq_ppl_kernel(const unsigned int* __restrict__ counts,
                                                      float* __restrict__ out) {
    __shared__ float red[16];
    int k = threadIdx.x;
    float p = (float)counts[k] / (float)NROWS;
    float v = p * logf(p + 1e-10f);
    #pragma unroll
    for (int off = 32; off > 0; off >>= 1) v += __shfl_down(v, off, 64);
    int wave = k >> 6;
    int lane = k & 63;
    if (lane == 0) red[wave] = v;
    __syncthreads();
    if (k == 0) {
        float sum = 0.f;
        #pragma unroll
        for (int w = 0; w < 16; w++) sum += red[w];
        float ppl = expf(-sum);
        out[8388608] = 0.0f;   // loss (eval branch)
        out[8388609] = ppl;    // perplexity
    }
}

extern "C" void kernel_launch(void* const* d_in, const int* in_sizes, int n_in,
                              void* d_out, int out_size, void* d_ws, size_t ws_size,
                              hipStream_t stream) {
    const float* x  = (const float*)d_in[0];
    const float* cb = (const float*)d_in[1];
    float* out = (float*)d_out;

    unsigned int* counts = (unsigned int*)d_ws;                 // 1024 u32
    float*        cc     = (float*)((char*)d_ws + 4096);        // 1024 f32

    hipMemsetAsync(d_ws, 0, 4096, stream);                      // zero histogram
    vq_cc_kernel<<<(KCODES + 255) / 256, 256, 0, stream>>>(cb, cc);
    vq_main_kernel<<<NROWS / 256, 256, 0, stream>>>(x, cb, cc, out, counts);
    vq_ppl_kernel<<<1, 1024, 0, stream>>>(counts, out);
}